// Round 11
// baseline (182.964 us; speedup 1.0000x reference)
//
#include <hip/hip_runtime.h>
#include <stdint.h>

#define SA 1027
#define SPAD 1088

typedef __attribute__((ext_vector_type(8))) short short8;
typedef __attribute__((ext_vector_type(4))) float f32x4;
typedef __attribute__((ext_vector_type(2))) unsigned int u32x2;

typedef const __attribute__((address_space(1))) uint8_t* gas1;
typedef __attribute__((address_space(3))) uint8_t* las3;

__device__ __forceinline__ void gload16(const void* g, void* l){
  __builtin_amdgcn_global_load_lds((gas1)g, (las3)l, 16, 0, 0);
}

__device__ __forceinline__ uint16_t f2bf(float f){
  uint32_t x = __builtin_bit_cast(uint32_t, f);
  x = (x + 0x7fffu + ((x >> 16) & 1u)) >> 16;
  return (uint16_t)x;
}
__device__ __forceinline__ float bf2f(uint16_t u){
  uint32_t x = ((uint32_t)u) << 16;
  return __builtin_bit_cast(float, x);
}

__device__ __forceinline__ f32x4 mfma16(short8 a, short8 b, f32x4 c){
  return __builtin_amdgcn_mfma_f32_16x16x32_bf16(a, b, c, 0, 0, 0);
}

// log2(e)/8 — folded into Q at the QKV GEMM epilogue
#define QSCALE 0.18033688011112042f

// ---------------- merged prep: weights->bf16 | X->bf16 | phys K/V rows ------
__global__ __launch_bounds__(256) void prep_all(
    const float* __restrict__ cnn, const float* __restrict__ llm,
    const float* __restrict__ Wq, const float* __restrict__ Wk,
    const float* __restrict__ Wv, const float* __restrict__ Wo,
    const float* __restrict__ bq, const float* __restrict__ bk,
    const float* __restrict__ bv, const float* __restrict__ bo,
    const float* __restrict__ ee, const float* __restrict__ em,
    const float* __restrict__ ep,
    uint16_t* __restrict__ W, float* __restrict__ bias,
    uint16_t* __restrict__ X, uint16_t* __restrict__ Yqk,
    uint16_t* __restrict__ Vt){
  const int bid = blockIdx.x;
  if (bid < 4100){
    const int gid = bid*256 + threadIdx.x;
    if (gid < 1048576){
      const int w = gid >> 18;
      const int off = (gid & 262143) << 2;
      const float* src = (w==0) ? Wq : (w==1) ? Wk : (w==2) ? Wv : Wo;
      const float4 v = *(const float4*)(src + off);
      ushort4 u;
      u.x = f2bf(v.x); u.y = f2bf(v.y); u.z = f2bf(v.z); u.w = f2bf(v.w);
      *(ushort4*)(W + ((size_t)w << 20) + off) = u;
    } else if (gid < 1048576 + 1024){
      const int i = (gid - 1048576) << 2;
      const int w = i >> 10;
      const int off = i & 1023;
      const float* src = (w==0) ? bq : (w==1) ? bk : (w==2) ? bv : bo;
      *(float4*)(bias + i) = *(const float4*)(src + off);
    }
  } else if (bid < 8196){
    const int rb = bid - 4100;
    const int row = rb*2 + (threadIdx.x >> 7);
    const int c8 = (threadIdx.x & 127) << 3;
    const int cb = row >> 10, s = row & 1023;
    const int c = cb >> 2, b = cb & 3;
    const float* src = (c ? llm : cnn) + ((size_t)(b*1024 + s))*1024 + c8;
    const float4 v0 = *(const float4*)src;
    const float4 v1 = *(const float4*)(src + 4);
    short8 u;
    u[0]=(short)f2bf(v0.x); u[1]=(short)f2bf(v0.y); u[2]=(short)f2bf(v0.z); u[3]=(short)f2bf(v0.w);
    u[4]=(short)f2bf(v1.x); u[5]=(short)f2bf(v1.y); u[6]=(short)f2bf(v1.z); u[7]=(short)f2bf(v1.w);
    *(short8*)(X + (size_t)row*1024 + c8) = u;
  } else {
    __shared__ float xs[1024];
    const int pb = bid - 8196;
    const int t = pb >> 3;
    const int col = 1024 + (pb & 7)*256 + threadIdx.x;   // 1024..3071
    const float* e = (t==0) ? ee : (t==1) ? em : ep;
    for (int k = threadIdx.x; k < 1024; k += 256) xs[k] = bf2f(f2bf(e[k]));
    __syncthreads();
    const float* wrow = (col < 2048) ? (Wk + (size_t)(col-1024)*1024)
                                     : (Wv + (size_t)(col-2048)*1024);
    const float bb = (col < 2048) ? bk[col-1024] : bv[col-2048];
    float acc = 0.f;
    for (int k = 0; k < 1024; k += 4){
      const float4 w4 = *(const float4*)(wrow + k);
      acc += bf2f(f2bf(w4.x))*xs[k] + bf2f(f2bf(w4.y))*xs[k+1]
           + bf2f(f2bf(w4.z))*xs[k+2] + bf2f(f2bf(w4.w))*xs[k+3];
    }
    const uint16_t o = f2bf(acc + bb);
    if (col < 2048){
      #pragma unroll
      for (int cb = 0; cb < 8; ++cb)
        Yqk[((size_t)cb*SA + 1024 + t)*2048 + col] = o;
    } else {
      const int hd = col - 2048;
      #pragma unroll
      for (int cb = 0; cb < 8; ++cb)
        Vt[((size_t)(cb*1024 + hd))*SPAD + 1024 + t] = o;
    }
  }
}

// ---------------- QKV: 128x192 2-phase GEMM, 80KB LDS -> 2 blocks/CU --------
// grid 1024. Within-XCD order: 2-bm superblocks (B-panel reused 2x per pass).
__global__ __launch_bounds__(512, 4) void qkv128(
    const uint16_t* __restrict__ A, const uint16_t* __restrict__ B,
    const float* __restrict__ bias, uint16_t* __restrict__ Yqk,
    uint16_t* __restrict__ Vt){
  extern __shared__ uint8_t lds[];   // buf b at b*40960: A 16KB, B at +16384 (24KB)
  const int tid = threadIdx.x;
  const int lane = tid & 63, wid = tid >> 6;
  const int l15 = lane & 15, l4 = lane >> 4;
  const int wm = wid >> 2, wn = wid & 3;
  const int xcd = blockIdx.x & 7, loc = blockIdx.x >> 3;   // loc 0..127
  const int sb = loc >> 5, pos = loc & 31;                 // 4 superblocks of 2bm x 16bn
  const int bm = xcd*8 + sb*2 + (pos & 1);
  const int bn = pos >> 1;

  const uint16_t* Ag = A + (size_t)bm*128*1024;
  const uint16_t* Bg = B + (size_t)bn*192*1024;

  const int srow8 = lane >> 3;
  const int gch = (lane & 7) ^ srow8;
  const int c0 = wid*2, c1 = c0 + 1;
  const size_t ga0 = (size_t)(c0*8 + srow8)*1024 + gch*8;
  const size_t ga1 = (size_t)(c1*8 + srow8)*1024 + gch*8;
  const size_t gb0 = (size_t)((wid*3+0)*8 + srow8)*1024 + gch*8;
  const size_t gb1 = (size_t)((wid*3+1)*8 + srow8)*1024 + gch*8;
  const size_t gb2 = (size_t)((wid*3+2)*8 + srow8)*1024 + gch*8;

#define STG_A(buf, kt) do { \
    gload16(Ag + (size_t)(kt)*64 + ga0, lds + (buf)*40960 + c0*1024); \
    gload16(Ag + (size_t)(kt)*64 + ga1, lds + (buf)*40960 + c1*1024); \
  } while(0)
#define STG_B(buf, kt) do { \
    gload16(Bg + (size_t)(kt)*64 + gb0, lds + (buf)*40960 + 16384 + (wid*3+0)*1024); \
    gload16(Bg + (size_t)(kt)*64 + gb1, lds + (buf)*40960 + 16384 + (wid*3+1)*1024); \
    gload16(Bg + (size_t)(kt)*64 + gb2, lds + (buf)*40960 + 16384 + (wid*3+2)*1024); \
  } while(0)

  int koff[2];
  koff[0] = (l4*16) ^ ((l15 & 7) << 4);
  koff[1] = (64 + l4*16) ^ ((l15 & 7) << 4);
  const int arow = (wm*64 + l15) * 128;
  const int bbase = 16384 + (wn*48 + l15) * 128;

  f32x4 acc[4][3];
  #pragma unroll
  for (int i = 0; i < 4; ++i)
    #pragma unroll
    for (int j = 0; j < 3; ++j) acc[i][j] = (f32x4){0.f,0.f,0.f,0.f};

  const int NT = 16;
  STG_A(0,0); STG_B(0,0); STG_B(1,1);
  asm volatile("s_waitcnt vmcnt(3)" ::: "memory");
  __builtin_amdgcn_s_barrier();

  for (int s = 0; s < NT; ++s){
    const int b = s & 1, nb = b ^ 1;
    const uint8_t* L = lds + b*40960;
    short8 af[2][2], af2[2][2], bfr[3][2];

    // ---- phase 0: rows wm*64+0..31 x all 3 B frags
    if (s+1 < NT){ STG_A(nb, s+1); }
    #pragma unroll
    for (int i = 0; i < 2; ++i){
      af[i][0] = *(const short8*)(L + arow + i*2048 + koff[0]);
      af[i][1] = *(const short8*)(L + arow + i*2048 + koff[1]);
    }
    #pragma unroll
    for (int j = 0; j < 3; ++j){
      bfr[j][0] = *(const short8*)(L + bbase + j*2048 + koff[0]);
      bfr[j][1] = *(const short8*)(L + bbase + j*2048 + koff[1]);
    }
    __builtin_amdgcn_s_barrier();
    asm volatile("s_waitcnt lgkmcnt(0)" ::: "memory");
    __builtin_amdgcn_s_setprio(1);
    #pragma unroll
    for (int i = 0; i < 2; ++i)
      #pragma unroll
      for (int j = 0; j < 3; ++j)
        acc[i][j] = mfma16(af[i][1], bfr[j][1], mfma16(af[i][0], bfr[j][0], acc[i][j]));
    __builtin_amdgcn_s_setprio(0);
    __builtin_amdgcn_s_barrier();

    // ---- phase 1: rows wm*64+32..63 (B frags reused from regs)
    if (s+2 < NT){ STG_B(b, s+2); }   // B(b) dead after phase-0 barrier
    #pragma unroll
    for (int i = 0; i < 2; ++i){
      af2[i][0] = *(const short8*)(L + arow + 4096 + i*2048 + koff[0]);
      af2[i][1] = *(const short8*)(L + arow + 4096 + i*2048 + koff[1]);
    }
    __builtin_amdgcn_s_barrier();
    asm volatile("s_waitcnt lgkmcnt(0)" ::: "memory");
    __builtin_amdgcn_s_setprio(1);
    #pragma unroll
    for (int i = 0; i < 2; ++i)
      #pragma unroll
      for (int j = 0; j < 3; ++j)
        acc[i+2][j] = mfma16(af2[i][1], bfr[j][1], mfma16(af2[i][0], bfr[j][0], acc[i+2][j]));
    __builtin_amdgcn_s_setprio(0);
    if (s < NT-2)       asm volatile("s_waitcnt vmcnt(3)" ::: "memory");
    else if (s == NT-2) asm volatile("s_waitcnt vmcnt(0)" ::: "memory");
    __builtin_amdgcn_s_barrier();
  }

  // epilogue: Q/K -> Yqk (row remap), V -> Vt transposed
  #pragma unroll
  for (int j = 0; j < 3; ++j){
    const int n = bn*192 + wn*48 + j*16 + l15;
    const float bb = bias[n];
    if (n < 2048){
      const float sc = (n < 1024) ? QSCALE : 1.0f;
      #pragma unroll
      for (int i = 0; i < 4; ++i){
        const int m0 = bm*128 + wm*64 + i*16 + l4*4;
        #pragma unroll
        for (int r = 0; r < 4; ++r){
          const int m = m0 + r;
          Yqk[((size_t)(m >> 10)*SA + (m & 1023))*2048 + n] = f2bf((acc[i][j][r] + bb) * sc);
        }
      }
    } else {
      const int hd = n - 2048;
      #pragma unroll
      for (int i = 0; i < 4; ++i){
        const int m0 = bm*128 + wm*64 + i*16 + l4*4;
        const size_t vrow = (size_t)(m0 >> 10)*1024 + hd;
        const uint32_t w0 = (uint32_t)f2bf(acc[i][j][0] + bb) | ((uint32_t)f2bf(acc[i][j][1] + bb) << 16);
        const uint32_t w1 = (uint32_t)f2bf(acc[i][j][2] + bb) | ((uint32_t)f2bf(acc[i][j][3] + bb) << 16);
        *(u32x2*)(Vt + vrow*SPAD + (m0 & 1023)) = (u32x2){w0, w1};
      }
    }
  }
#undef STG_A
#undef STG_B
}

// ---------------- oproj: 256x128 2-phase GEMM (R9 proven), grid 256 ---------
__global__ __launch_bounds__(512, 2) void oproj256(
    const uint16_t* __restrict__ A, const uint16_t* __restrict__ B,
    const float* __restrict__ bias, uint16_t* __restrict__ C){
  extern __shared__ uint8_t lds[];   // buf b at b*49152: A 32KB, B at +32768
  const int tid = threadIdx.x;
  const int lane = tid & 63, wid = tid >> 6;
  const int l15 = lane & 15, l4 = lane >> 4;
  const int wm = wid >> 2, wn = wid & 3;
  const int wg = (blockIdx.x & 7)*32 + (blockIdx.x >> 3);   // 256 blocks
  const int bm = wg >> 3, bn = wg & 7;

  const uint16_t* Ag = A + (size_t)bm*256*1024;
  const uint16_t* Bg = B + (size_t)bn*128*1024;

  const int srow8 = lane >> 3;
  const int gch = (lane & 7) ^ srow8;
  const int c0 = wid*2, c1 = c0 + 1;
  const size_t ga0 = (size_t)(c0*8 + srow8)*1024 + gch*8;
  const size_t ga1 = (size_t)(c1*8 + srow8)*1024 + gch*8;

#define STG_A(buf, H, kt) do { \
    gload16(Ag + (size_t)(H)*131072 + (size_t)(kt)*64 + ga0, lds + (buf)*49152 + (H)*16384 + c0*1024); \
    gload16(Ag + (size_t)(H)*131072 + (size_t)(kt)*64 + ga1, lds + (buf)*49152 + (H)*16384 + c1*1024); \
  } while(0)
#define STG_B(buf, kt) do { \
    gload16(Bg + (size_t)(kt)*64 + ga0, lds + (buf)*49152 + 32768 + c0*1024); \
    gload16(Bg + (size_t)(kt)*64 + ga1, lds + (buf)*49152 + 32768 + c1*1024); \
  } while(0)

  int koff[2];
  koff[0] = (l4*16) ^ ((l15 & 7) << 4);
  koff[1] = (64 + l4*16) ^ ((l15 & 7) << 4);
  const int abase = wm*16384 + l15*128;
  const int bbase = 32768 + (wn*32 + l15)*128;

  f32x4 acc[8][2];
  #pragma unroll
  for (int i = 0; i < 8; ++i){ acc[i][0] = (f32x4){0,0,0,0}; acc[i][1] = (f32x4){0,0,0,0}; }

  const int NT = 16;
  STG_A(0,0,0); STG_A(0,1,0); STG_B(0,0); STG_B(1,1);
  asm volatile("s_waitcnt vmcnt(2)" ::: "memory");
  __builtin_amdgcn_s_barrier();

  for (int s = 0; s < NT; ++s){
    const int b = s & 1, nb = b ^ 1;
    const uint8_t* L = lds + b*49152;
    short8 af[4][2], af2[4][2], bfr[2][2];

    // ---- phase 0
    if (s+1 < NT){ STG_A(nb, 0, s+1); }
    #pragma unroll
    for (int i = 0; i < 4; ++i){
      af[i][0] = *(const short8*)(L + abase + i*2048 + koff[0]);
      af[i][1] = *(const short8*)(L + abase + i*2048 + koff[1]);
    }
    #pragma unroll
    for (int j = 0; j < 2; ++j){
      bfr[j][0] = *(const short8*)(L + bbase + j*2048 + koff[0]);
      bfr[j][1] = *(const short8*)(L + bbase + j*2048 + koff[1]);
    }
    __builtin_amdgcn_s_barrier();
    asm volatile("s_waitcnt lgkmcnt(0)" ::: "memory");
    __builtin_amdgcn_s_setprio(1);
    #pragma unroll
    for (int i = 0; i < 4; ++i)
      #pragma unroll
      for (int j = 0; j < 2; ++j)
        acc[i][j] = mfma16(af[i][1], bfr[j][1], mfma16(af[i][0], bfr[j][0], acc[i][j]));
    __builtin_amdgcn_s_setprio(0);
    __builtin_amdgcn_s_barrier();

    // ---- phase 1
    if (s+1 < NT){ STG_A(nb, 1, s+1); }
    if (s+2 < NT){ STG_B(b, s+2); }
    #pragma unroll
    for (int i = 0; i < 4; ++i){
      af2[i][0] = *(const short8*)(L + abase + 8192 + i*2048 + koff[0]);
      af2[i][1] = *(const short8*)(L + abase + 8192 + i*2048 + koff[1]);
    }
    __builtin_amdgcn_s_barrier();
    asm volatile("s_waitcnt lgkmcnt(0)" ::: "memory");
    __builtin_amdgcn_s_setprio(1);
    #pragma unroll
    for (int i = 0; i < 4; ++i)
      #pragma unroll
      for (int j = 0; j < 2; ++j)
        acc[i+4][j] = mfma16(af2[i][1], bfr[j][1], mfma16(af2[i][0], bfr[j][0], acc[i+4][j]));
    __builtin_amdgcn_s_setprio(0);
    if (s < NT-2)       asm volatile("s_waitcnt vmcnt(2)" ::: "memory");
    else if (s == NT-2) asm volatile("s_waitcnt vmcnt(0)" ::: "memory");
    __builtin_amdgcn_s_barrier();
  }

  #pragma unroll
  for (int j = 0; j < 2; ++j){
    const int n = bn*128 + wn*32 + j*16 + l15;
    const float bb = bias[n];
    #pragma unroll
    for (int i = 0; i < 8; ++i){
      const size_t m0 = (size_t)bm*256 + wm*128 + i*16 + l4*4;
      #pragma unroll
      for (int r = 0; r < 4; ++r)
        C[(m0 + r)*1024 + n] = f2bf(acc[i][j][r] + bb);
    }
  }
#undef STG_A
#undef STG_B
}

// ---------------- flash attention: 3-buffer K/V ring, counted vmcnt ----------
__global__ __launch_bounds__(512, 4) void attn_k(
    const uint16_t* __restrict__ Yqk, const uint16_t* __restrict__ Vt,
    uint16_t* __restrict__ att){
  extern __shared__ uint8_t lds[];
  const int tid = threadIdx.x;
  const int lane = tid & 63, wid = tid >> 6;
  const int l15 = lane & 15, l4 = lane >> 4;
  const int i = blockIdx.x;
  const int inst = (i & 7)*16 + ((i >> 3) & 15);
  const int qb = i >> 7;
  const int h = inst & 15, cb = inst >> 4;
  const size_t yrow0 = (size_t)cb * SA;
  const int q0 = qb*256 + wid*32;
  const size_t vbase = (size_t)inst * 64 * SPAD;
  const uint16_t* Yk = Yqk + yrow0*2048 + 1024 + h*64;

  short8 qf[2][2];
  #pragma unroll
  for (int u = 0; u < 2; ++u){
    const uint16_t* p = Yqk + (yrow0 + q0 + u*16 + l15)*2048 + h*64 + l4*8;
    qf[u][0] = *(const short8*)p;
    qf[u][1] = *(const short8*)(p + 32);
  }

  f32x4 o0[4], o1[4];
  float psum0 = 0.f, psum1 = 0.f;
  #pragma unroll
  for (int d = 0; d < 4; ++d){ o0[d] = (f32x4){0,0,0,0}; o1[d] = (f32x4){0,0,0,0}; }

  int koff[2], koffp[2], pwo[4];
  #pragma unroll
  for (int kk = 0; kk < 2; ++kk){
    koff[kk]  = (l15*128 + kk*64 + l4*16) ^ ((l15 & 7) << 4);
    koffp[kk] = l15*144 + kk*64 + l4*16;
  }
  #pragma unroll
  for (int nt = 0; nt < 4; ++nt)
    pwo[nt] = l15*144 + nt*32 + l4*8;
  uint8_t* const pb = lds + 49152 + wid*2304;

  const int srow = lane >> 3, schunk = lane & 7;
  const int strow = wid*8 + srow;
  const int sgch = schunk ^ srow;

#define ASTAGE(t3, kt) do { \
    gload16(Yk + (size_t)((kt)*64 + strow)*2048 + sgch*8, lds + (t3)*8192 + wid*1024); \
    gload16(Vt + vbase + (size_t)strow*SPAD + (kt)*64 + sgch*8, lds + 24576 + (t3)*8192 + wid*1024); \
  } while(0)

  ASTAGE(0, 0);
  ASTAGE(1, 1);
  asm volatile("s_waitcnt vmcnt(2)" ::: "memory");
  __builtin_amdgcn_s_barrier();

  for (int kt = 0; kt < 17; ++kt){
    const int c3 = kt % 3;
    if (kt <= 14){ const int t3 = (kt + 2) % 3; ASTAGE(t3, kt + 2); }
    const uint8_t* bK = lds + c3*8192;
    const uint8_t* bV = lds + 24576 + c3*8192;

    f32x4 sa[4], sb[4];
    #pragma unroll
    for (int nt = 0; nt < 4; ++nt){
      const short8 k0 = *(const short8*)(bK + nt*2048 + koff[0]);
      const short8 k1 = *(const short8*)(bK + nt*2048 + koff[1]);
      sa[nt] = mfma16(k1, qf[0][1], mfma16(k0, qf[0][0], (f32x4){0,0,0,0}));
      sb[nt] = mfma16(k1, qf[1][1], mfma16(k0, qf[1][0], (f32x4){0,0,0,0}));
    }
    if (kt == 16){
      #pragma unroll
      for (int nt = 0; nt < 4; ++nt)
        #pragma unroll
        for (int r = 0; r < 4; ++r){
          if (nt*16 + l4*4 + r >= 3){ sa[nt][r] = -3e38f; sb[nt][r] = -3e38f; }
        }
    }
    #pragma unroll
    for (int nt = 0; nt < 4; ++nt){
      const float p0 = __builtin_amdgcn_exp2f(sa[nt][0]);
      const float p1 = __builtin_amdgcn_exp2f(sa[nt][1]);
      const float p2 = __builtin_amdgcn_exp2f(sa[nt][2]);
      const float p3 = __builtin_amdgcn_exp2f(sa[nt][3]);
      psum0 += (p0 + p1) + (p2 + p3);
      uint32_t w0, w1;
      asm("v_cvt_pk_bf16_f32 %0, %1, %2" : "=v"(w0) : "v"(p0), "v"(p1));
      asm("v_cvt_pk_bf16_f32 %0, %1, %2" : "=v"(w1) : "v"(p2), "v"(p3));
      *(u32x2*)(pb + pwo[nt]) = (u32x2){w0, w1};
    }
    short8 vf[4][2];
    #pragma unroll
    for (int dt = 0; dt < 4; ++dt){
      vf[dt][0] = *(const short8*)(bV + dt*2048 + koff[0]);
      vf[dt][1] = *(const short8*)(bV + dt*2048 + koff[1]);
    }
    #pragma unroll
    for (int kk = 0; kk < 2; ++kk){
      const short8 pf = *(const short8*)(pb + koffp[kk]);
      #pragma unroll
      for (int dt = 0; dt < 4; ++dt)
        o0[dt] = mfma16(pf, vf[dt][kk], o0[dt]);
    }
    #pragma unroll
    for (int nt = 0; nt < 4; ++nt){
      const float p0 = __builtin_amdgcn_exp2f(sb[nt][0]);
      const float p1 = __builtin_amdgcn_exp2f(sb[nt][1]);
      const float p2 = __builtin_amdgcn_exp2f(sb[nt][2]);
      const float p3 = __builtin_amdgcn_exp2f(sb[nt][3]);
      psum1 += (p0 + p1) + (p2 + p3);
      uint32_t w0, w1;
      asm("v_cvt_pk_bf16_f32 %0, %1, %2" : "=v"(w0) : "v"(p0), "v"(p1));
      asm("v_cvt_pk_bf16_f32 %0, %1, %2" : "=v"(w1) : "v"(p2), "v"(p3));
      *(u32x2*)(pb + pwo[nt]) = (u32x2){w0, w1};
    }
    #pragma unroll
    for (int kk = 0; kk < 2; ++kk){
      const short8 pf = *(const short8*)(pb + koffp[kk]);
      #pragma unroll
      for (int dt = 0; dt < 4; ++dt)
        o1[dt] = mfma16(pf, vf[dt][kk], o1[dt]);
    }
    if (kt <= 14)      asm volatile("s_waitcnt vmcnt(2)" ::: "memory");
    else if (kt == 15) asm volatile("s_waitcnt vmcnt(0)" ::: "memory");
    if (kt <= 15) __builtin_amdgcn_s_barrier();
  }
#undef ASTAGE

  psum0 += __shfl_xor(psum0, 16); psum0 += __shfl_xor(psum0, 32);
  psum1 += __shfl_xor(psum1, 16); psum1 += __shfl_xor(psum1, 32);
  const size_t arow0 = (size_t)cb*1024 + q0;
  #pragma unroll
  for (int r = 0; r < 4; ++r){
    const float inv0 = 1.f / __shfl(psum0, l4*4 + r);
    const float inv1 = 1.f / __shfl(psum1, l4*4 + r);
    #pragma unroll
    for (int dt = 0; dt < 4; ++dt){
      att[(arow0 + l4*4 + r)*1024 + h*64 + dt*16 + l15] = f2bf(o0[dt][r] * inv0);
      att[(arow0 + 16 + l4*4 + r)*1024 + h*64 + dt*16 + l15] = f2bf(o1[dt][r] * inv1);
    }
  }
}

// ---------------- fused residual + LayerNorm -> f32 out ----------------
__global__ __launch_bounds__(256) void ln_out(
    const uint16_t* __restrict__ Op, const float* __restrict__ cnn,
    const float* __restrict__ llm, const float* __restrict__ g,
    const float* __restrict__ b, float* __restrict__ out){
  const int row = blockIdx.x;
  const int c = row >> 12, bq = row & 4095;
  const int tid = threadIdx.x;
  const ushort4 u = *(const ushort4*)(Op + (size_t)row*1024 + (tid<<2));
  const float4 rv = *(const float4*)((c ? llm : cnn) + (size_t)bq*1024 + (tid<<2));
  const float x0 = bf2f(u.x) + rv.x;
  const float x1 = bf2f(u.y) + rv.y;
  const float x2 = bf2f(u.z) + rv.z;
  const float x3 = bf2f(u.w) + rv.w;
  float s1 = x0+x1+x2+x3;
  float s2 = x0*x0+x1*x1+x2*x2+x3*x3;
  #pragma unroll
  for (int m=1;m<64;m<<=1){ s1 += __shfl_xor(s1,m); s2 += __shfl_xor(s2,m); }
  __shared__ float r1[4], r2[4];
  const int wid = tid >> 6, lane = tid & 63;
  if (lane == 0){ r1[wid] = s1; r2[wid] = s2; }
  __syncthreads();
  s1 = r1[0]+r1[1]+r1[2]+r1[3];
  s2 = r2[0]+r2[1]+r2[2]+r2[3];
  const float mu = s1 * 0.0009765625f;
  const float var = s2 * 0.0009765625f - mu*mu;
  const float rs = rsqrtf(var + 1e-5f);
  const float4 gv = *(const float4*)(g + (tid<<2));
  const float4 bv = *(const float4*)(b + (tid<<2));
  float4 ov;
  ov.x = (x0 - mu)*rs*gv.x + bv.x;
  ov.y = (x1 - mu)*rs*gv.y + bv.y;
  ov.z = (x2 - mu)*rs*gv.z + bv.z;
  ov.w = (x3 - mu)*rs*gv.w + bv.w;
  *(float4*)(out + ((size_t)c << 22) + (size_t)bq*1024 + (tid<<2)) = ov;
}

extern "C" void kernel_launch(void* const* d_in, const int* in_sizes, int n_in,
                              void* d_out, int out_size, void* d_ws, size_t ws_size,
                              hipStream_t stream){
  const float* cnn = (const float*)d_in[0];
  const float* llm = (const float*)d_in[1];
  const float* Wq  = (const float*)d_in[2];
  const float* bq  = (const float*)d_in[3];
  const float* Wk  = (const float*)d_in[4];
  const float* bk  = (const float*)d_in[5];
  const float* Wv  = (const float*)d_in[6];
  const float* bv  = (const float*)d_in[7];
  const float* Wo  = (const float*)d_in[8];
  const float* bo  = (const float*)d_in[9];
  const float* lng = (const float*)d_in[10];
  const float* lnb = (const float*)d_in[11];
  const float* ee  = (const float*)d_in[12];
  const float* em  = (const float*)d_in[13];
  const float* ep  = (const float*)d_in[14];

  uint8_t* ws = (uint8_t*)d_ws;
  uint16_t* X    = (uint16_t*)(ws + 0);           // 8192*1024*2 = 16,777,216
  uint16_t* W    = (uint16_t*)(ws + 16777216);    //  8,388,608
  float*    bias = (float*)   (ws + 25165824);    //     16,384
  uint16_t* Yqk  = (uint16_t*)(ws + 25182208);    // 8448*2048*2 = 34,603,008
  uint16_t* Vt   = (uint16_t*)(ws + 59785216);    // 8192*1088*2 = 17,825,792
  uint16_t* att  = X;                              // X dead after QKV GEMM
  uint16_t* Op   = Yqk;                            // Yqk dead after attn
  float* out = (float*)d_out;

  hipFuncSetAttribute((const void*)qkv128,
                      hipFuncAttributeMaxDynamicSharedMemorySize, 81920);
  hipFuncSetAttribute((const void*)oproj256,
                      hipFuncAttributeMaxDynamicSharedMemorySize, 98304);
  hipFuncSetAttribute((const void*)attn_k,
                      hipFuncAttributeMaxDynamicSharedMemorySize, 67584);

  prep_all<<<8220, 256, 0, stream>>>(cnn, llm, Wq, Wk, Wv, Wo, bq, bk, bv, bo,
                                     ee, em, ep, W, bias, X, Yqk, Vt);
  qkv128<<<1024, 512, 81920, stream>>>(X, W, bias, Yqk, Vt);
  attn_k<<<512, 512, 67584, stream>>>(Yqk, Vt, att);
  oproj256<<<256, 512, 98304, stream>>>(att, W + 3145728, bias + 3072, Op);
  ln_out<<<8192, 256, 0, stream>>>(Op, cnn, llm, lng, lnb, out);
}

// Round 12
// 172.331 us; speedup vs baseline: 1.0617x; 1.0617x over previous
//
#include <hip/hip_runtime.h>
#include <stdint.h>

#define SA 1027
#define SPAD 1088

typedef __attribute__((ext_vector_type(8))) short short8;
typedef __attribute__((ext_vector_type(4))) float f32x4;
typedef __attribute__((ext_vector_type(2))) unsigned int u32x2;

typedef const __attribute__((address_space(1))) uint8_t* gas1;
typedef __attribute__((address_space(3))) uint8_t* las3;

__device__ __forceinline__ void gload16(const void* g, void* l){
  __builtin_amdgcn_global_load_lds((gas1)g, (las3)l, 16, 0, 0);
}

__device__ __forceinline__ uint16_t f2bf(float f){
  uint32_t x = __builtin_bit_cast(uint32_t, f);
  x = (x + 0x7fffu + ((x >> 16) & 1u)) >> 16;
  return (uint16_t)x;
}
__device__ __forceinline__ float bf2f(uint16_t u){
  uint32_t x = ((uint32_t)u) << 16;
  return __builtin_bit_cast(float, x);
}

__device__ __forceinline__ f32x4 mfma16(short8 a, short8 b, f32x4 c){
  return __builtin_amdgcn_mfma_f32_16x16x32_bf16(a, b, c, 0, 0, 0);
}

// log2(e)/8 — folded into Q at the QKV GEMM epilogue
#define QSCALE 0.18033688011112042f

// ---------------- prep: weights/biases -> bf16 ws ----------------
__global__ __launch_bounds__(256) void prep_wb(
    const float* __restrict__ Wq, const float* __restrict__ Wk,
    const float* __restrict__ Wv, const float* __restrict__ Wo,
    const float* __restrict__ bq, const float* __restrict__ bk,
    const float* __restrict__ bv, const float* __restrict__ bo,
    uint16_t* __restrict__ W, float* __restrict__ bias){
  const int gid = blockIdx.x*256 + threadIdx.x;
  if (gid < 1048576){
    const int w = gid >> 18;
    const int off = (gid & 262143) << 2;
    const float* src = (w==0) ? Wq : (w==1) ? Wk : (w==2) ? Wv : Wo;
    const float4 v = *(const float4*)(src + off);
    ushort4 u;
    u.x = f2bf(v.x); u.y = f2bf(v.y); u.z = f2bf(v.z); u.w = f2bf(v.w);
    *(ushort4*)(W + ((size_t)w << 20) + off) = u;
  } else if (gid < 1048576 + 1024){
    const int i = (gid - 1048576) << 2;
    const int w = i >> 10;
    const int off = i & 1023;
    const float* src = (w==0) ? bq : (w==1) ? bk : (w==2) ? bv : bo;
    *(float4*)(bias + i) = *(const float4*)(src + off);
  }
}

// ---------------- prep: X = seq rows (8192) bf16; 2 rows/block ----------------
__global__ __launch_bounds__(256) void prep_X(
    const float* __restrict__ cnn, const float* __restrict__ llm,
    uint16_t* __restrict__ X){
  const int row = blockIdx.x*2 + (threadIdx.x >> 7);
  const int c8 = (threadIdx.x & 127) << 3;
  const int cb = row >> 10, s = row & 1023;
  const int c = cb >> 2, b = cb & 3;
  const float* src = (c ? llm : cnn) + ((size_t)(b*1024 + s))*1024 + c8;
  const float4 v0 = *(const float4*)src;
  const float4 v1 = *(const float4*)(src + 4);
  short8 u;
  u[0]=(short)f2bf(v0.x); u[1]=(short)f2bf(v0.y); u[2]=(short)f2bf(v0.z); u[3]=(short)f2bf(v0.w);
  u[4]=(short)f2bf(v1.x); u[5]=(short)f2bf(v1.y); u[6]=(short)f2bf(v1.z); u[7]=(short)f2bf(v1.w);
  *(short8*)(X + (size_t)row*1024 + c8) = u;
}

// ---------------- phys rows: K,V projections of the 3 shared physics rows ----
__global__ __launch_bounds__(256) void phys_qkv(
    const float* __restrict__ ee, const float* __restrict__ em,
    const float* __restrict__ ep, const uint16_t* __restrict__ W,
    const float* __restrict__ bias, uint16_t* __restrict__ Yqk,
    uint16_t* __restrict__ Vt){
  __shared__ float xs[1024];
  const int t = blockIdx.x >> 3;
  const int col = 1024 + (blockIdx.x & 7)*256 + threadIdx.x;   // 1024..3071
  const float* e = (t==0) ? ee : (t==1) ? em : ep;
  for (int k = threadIdx.x; k < 1024; k += 256) xs[k] = bf2f(f2bf(e[k]));
  __syncthreads();
  const uint16_t* wr = W + (size_t)col*1024;
  float acc = 0.f;
  for (int k = 0; k < 1024; k += 8){
    const short8 w8 = *(const short8*)(wr + k);
    #pragma unroll
    for (int u = 0; u < 8; ++u) acc += bf2f((uint16_t)w8[u]) * xs[k+u];
  }
  const uint16_t o = f2bf(acc + bias[col]);
  if (col < 2048){
    #pragma unroll
    for (int cb = 0; cb < 8; ++cb)
      Yqk[((size_t)cb*SA + 1024 + t)*2048 + col] = o;
  } else {
    const int hd = col - 2048;
    #pragma unroll
    for (int cb = 0; cb < 8; ++cb)
      Vt[((size_t)(cb*1024 + hd))*SPAD + 1024 + t] = o;
  }
}

// ---------------- QKV: 128x192 2-phase GEMM, 80KB LDS -> 2 blocks/CU --------
// M=8192 N=3072 K=1024. grid 1024 = 64bm x 16bn = 4 exact rounds at 2/CU.
// 8 waves (2M x 4N), wave tile 64x48, acc[4][3]. Proven 58.4us (R10).
__global__ __launch_bounds__(512, 4) void qkv128(
    const uint16_t* __restrict__ A, const uint16_t* __restrict__ B,
    const float* __restrict__ bias, uint16_t* __restrict__ Yqk,
    uint16_t* __restrict__ Vt){
  extern __shared__ uint8_t lds[];   // buf b at b*40960: A 16KB, B at +16384 (24KB)
  const int tid = threadIdx.x;
  const int lane = tid & 63, wid = tid >> 6;
  const int l15 = lane & 15, l4 = lane >> 4;
  const int wm = wid >> 2, wn = wid & 3;
  const int wg = (blockIdx.x & 7)*128 + (blockIdx.x >> 3);
  const int bm = wg >> 4, bn = wg & 15;

  const uint16_t* Ag = A + (size_t)bm*128*1024;
  const uint16_t* Bg = B + (size_t)bn*192*1024;

  const int srow8 = lane >> 3;
  const int gch = (lane & 7) ^ srow8;
  const int c0 = wid*2, c1 = c0 + 1;
  const size_t ga0 = (size_t)(c0*8 + srow8)*1024 + gch*8;
  const size_t ga1 = (size_t)(c1*8 + srow8)*1024 + gch*8;
  const size_t gb0 = (size_t)((wid*3+0)*8 + srow8)*1024 + gch*8;
  const size_t gb1 = (size_t)((wid*3+1)*8 + srow8)*1024 + gch*8;
  const size_t gb2 = (size_t)((wid*3+2)*8 + srow8)*1024 + gch*8;

#define STG_A(buf, kt) do { \
    gload16(Ag + (size_t)(kt)*64 + ga0, lds + (buf)*40960 + c0*1024); \
    gload16(Ag + (size_t)(kt)*64 + ga1, lds + (buf)*40960 + c1*1024); \
  } while(0)
#define STG_B(buf, kt) do { \
    gload16(Bg + (size_t)(kt)*64 + gb0, lds + (buf)*40960 + 16384 + (wid*3+0)*1024); \
    gload16(Bg + (size_t)(kt)*64 + gb1, lds + (buf)*40960 + 16384 + (wid*3+1)*1024); \
    gload16(Bg + (size_t)(kt)*64 + gb2, lds + (buf)*40960 + 16384 + (wid*3+2)*1024); \
  } while(0)

  int koff[2];
  koff[0] = (l4*16) ^ ((l15 & 7) << 4);
  koff[1] = (64 + l4*16) ^ ((l15 & 7) << 4);
  const int arow = (wm*64 + l15) * 128;
  const int bbase = 16384 + (wn*48 + l15) * 128;

  f32x4 acc[4][3];
  #pragma unroll
  for (int i = 0; i < 4; ++i)
    #pragma unroll
    for (int j = 0; j < 3; ++j) acc[i][j] = (f32x4){0.f,0.f,0.f,0.f};

  const int NT = 16;
  STG_A(0,0); STG_B(0,0); STG_B(1,1);
  asm volatile("s_waitcnt vmcnt(3)" ::: "memory");
  __builtin_amdgcn_s_barrier();

  for (int s = 0; s < NT; ++s){
    const int b = s & 1, nb = b ^ 1;
    const uint8_t* L = lds + b*40960;
    short8 af[2][2], af2[2][2], bfr[3][2];

    // ---- phase 0: rows wm*64+0..31 x all 3 B frags
    if (s+1 < NT){ STG_A(nb, s+1); }
    #pragma unroll
    for (int i = 0; i < 2; ++i){
      af[i][0] = *(const short8*)(L + arow + i*2048 + koff[0]);
      af[i][1] = *(const short8*)(L + arow + i*2048 + koff[1]);
    }
    #pragma unroll
    for (int j = 0; j < 3; ++j){
      bfr[j][0] = *(const short8*)(L + bbase + j*2048 + koff[0]);
      bfr[j][1] = *(const short8*)(L + bbase + j*2048 + koff[1]);
    }
    __builtin_amdgcn_s_barrier();
    asm volatile("s_waitcnt lgkmcnt(0)" ::: "memory");
    __builtin_amdgcn_s_setprio(1);
    #pragma unroll
    for (int i = 0; i < 2; ++i)
      #pragma unroll
      for (int j = 0; j < 3; ++j)
        acc[i][j] = mfma16(af[i][1], bfr[j][1], mfma16(af[i][0], bfr[j][0], acc[i][j]));
    __builtin_amdgcn_s_setprio(0);
    __builtin_amdgcn_s_barrier();

    // ---- phase 1: rows wm*64+32..63 (B frags reused from regs)
    if (s+2 < NT){ STG_B(b, s+2); }   // B(b) dead after phase-0 barrier
    #pragma unroll
    for (int i = 0; i < 2; ++i){
      af2[i][0] = *(const short8*)(L + arow + 4096 + i*2048 + koff[0]);
      af2[i][1] = *(const short8*)(L + arow + 4096 + i*2048 + koff[1]);
    }
    __builtin_amdgcn_s_barrier();
    asm volatile("s_waitcnt lgkmcnt(0)" ::: "memory");
    __builtin_amdgcn_s_setprio(1);
    #pragma unroll
    for (int i = 0; i < 2; ++i)
      #pragma unroll
      for (int j = 0; j < 3; ++j)
        acc[i+2][j] = mfma16(af2[i][1], bfr[j][1], mfma16(af2[i][0], bfr[j][0], acc[i+2][j]));
    __builtin_amdgcn_s_setprio(0);
    if (s < NT-2)       asm volatile("s_waitcnt vmcnt(3)" ::: "memory");
    else if (s == NT-2) asm volatile("s_waitcnt vmcnt(0)" ::: "memory");
    __builtin_amdgcn_s_barrier();
  }

  // epilogue: Q/K -> Yqk (row remap), V -> Vt transposed
  #pragma unroll
  for (int j = 0; j < 3; ++j){
    const int n = bn*192 + wn*48 + j*16 + l15;
    const float bb = bias[n];
    if (n < 2048){
      const float sc = (n < 1024) ? QSCALE : 1.0f;
      #pragma unroll
      for (int i = 0; i < 4; ++i){
        const int m0 = bm*128 + wm*64 + i*16 + l4*4;
        #pragma unroll
        for (int r = 0; r < 4; ++r){
          const int m = m0 + r;
          Yqk[((size_t)(m >> 10)*SA + (m & 1023))*2048 + n] = f2bf((acc[i][j][r] + bb) * sc);
        }
      }
    } else {
      const int hd = n - 2048;
      #pragma unroll
      for (int i = 0; i < 4; ++i){
        const int m0 = bm*128 + wm*64 + i*16 + l4*4;
        const size_t vrow = (size_t)(m0 >> 10)*1024 + hd;
        const uint32_t w0 = (uint32_t)f2bf(acc[i][j][0] + bb) | ((uint32_t)f2bf(acc[i][j][1] + bb) << 16);
        const uint32_t w1 = (uint32_t)f2bf(acc[i][j][2] + bb) | ((uint32_t)f2bf(acc[i][j][3] + bb) << 16);
        *(u32x2*)(Vt + vrow*SPAD + (m0 & 1023)) = (u32x2){w0, w1};
      }
    }
  }
#undef STG_A
#undef STG_B
}

// ---------------- oproj: 256x128 2-phase GEMM (R9 proven), grid 256 ---------
__global__ __launch_bounds__(512, 2) void oproj256(
    const uint16_t* __restrict__ A, const uint16_t* __restrict__ B,
    const float* __restrict__ bias, uint16_t* __restrict__ C){
  extern __shared__ uint8_t lds[];   // buf b at b*49152: A 32KB, B at +32768
  const int tid = threadIdx.x;
  const int lane = tid & 63, wid = tid >> 6;
  const int l15 = lane & 15, l4 = lane >> 4;
  const int wm = wid >> 2, wn = wid & 3;
  const int wg = (blockIdx.x & 7)*32 + (blockIdx.x >> 3);   // 256 blocks
  const int bm = wg >> 3, bn = wg & 7;

  const uint16_t* Ag = A + (size_t)bm*256*1024;
  const uint16_t* Bg = B + (size_t)bn*128*1024;

  const int srow8 = lane >> 3;
  const int gch = (lane & 7) ^ srow8;
  const int c0 = wid*2, c1 = c0 + 1;
  const size_t ga0 = (size_t)(c0*8 + srow8)*1024 + gch*8;
  const size_t ga1 = (size_t)(c1*8 + srow8)*1024 + gch*8;

#define STG_A(buf, H, kt) do { \
    gload16(Ag + (size_t)(H)*131072 + (size_t)(kt)*64 + ga0, lds + (buf)*49152 + (H)*16384 + c0*1024); \
    gload16(Ag + (size_t)(H)*131072 + (size_t)(kt)*64 + ga1, lds + (buf)*49152 + (H)*16384 + c1*1024); \
  } while(0)
#define STG_B(buf, kt) do { \
    gload16(Bg + (size_t)(kt)*64 + ga0, lds + (buf)*49152 + 32768 + c0*1024); \
    gload16(Bg + (size_t)(kt)*64 + ga1, lds + (buf)*49152 + 32768 + c1*1024); \
  } while(0)

  int koff[2];
  koff[0] = (l4*16) ^ ((l15 & 7) << 4);
  koff[1] = (64 + l4*16) ^ ((l15 & 7) << 4);
  const int abase = wm*16384 + l15*128;
  const int bbase = 32768 + (wn*32 + l15)*128;

  f32x4 acc[8][2];
  #pragma unroll
  for (int i = 0; i < 8; ++i){ acc[i][0] = (f32x4){0,0,0,0}; acc[i][1] = (f32x4){0,0,0,0}; }

  const int NT = 16;
  STG_A(0,0,0); STG_A(0,1,0); STG_B(0,0); STG_B(1,1);
  asm volatile("s_waitcnt vmcnt(2)" ::: "memory");
  __builtin_amdgcn_s_barrier();

  for (int s = 0; s < NT; ++s){
    const int b = s & 1, nb = b ^ 1;
    const uint8_t* L = lds + b*49152;
    short8 af[4][2], af2[4][2], bfr[2][2];

    // ---- phase 0
    if (s+1 < NT){ STG_A(nb, 0, s+1); }
    #pragma unroll
    for (int i = 0; i < 4; ++i){
      af[i][0] = *(const short8*)(L + abase + i*2048 + koff[0]);
      af[i][1] = *(const short8*)(L + abase + i*2048 + koff[1]);
    }
    #pragma unroll
    for (int j = 0; j < 2; ++j){
      bfr[j][0] = *(const short8*)(L + bbase + j*2048 + koff[0]);
      bfr[j][1] = *(const short8*)(L + bbase + j*2048 + koff[1]);
    }
    __builtin_amdgcn_s_barrier();
    asm volatile("s_waitcnt lgkmcnt(0)" ::: "memory");
    __builtin_amdgcn_s_setprio(1);
    #pragma unroll
    for (int i = 0; i < 4; ++i)
      #pragma unroll
      for (int j = 0; j < 2; ++j)
        acc[i][j] = mfma16(af[i][1], bfr[j][1], mfma16(af[i][0], bfr[j][0], acc[i][j]));
    __builtin_amdgcn_s_setprio(0);
    __builtin_amdgcn_s_barrier();

    // ---- phase 1
    if (s+1 < NT){ STG_A(nb, 1, s+1); }
    if (s+2 < NT){ STG_B(b, s+2); }
    #pragma unroll
    for (int i = 0; i < 4; ++i){
      af2[i][0] = *(const short8*)(L + abase + 8192 + i*2048 + koff[0]);
      af2[i][1] = *(const short8*)(L + abase + 8192 + i*2048 + koff[1]);
    }
    __builtin_amdgcn_s_barrier();
    asm volatile("s_waitcnt lgkmcnt(0)" ::: "memory");
    __builtin_amdgcn_s_setprio(1);
    #pragma unroll
    for (int i = 0; i < 4; ++i)
      #pragma unroll
      for (int j = 0; j < 2; ++j)
        acc[i+4][j] = mfma16(af2[i][1], bfr[j][1], mfma16(af2[i][0], bfr[j][0], acc[i+4][j]));
    __builtin_amdgcn_s_setprio(0);
    if (s < NT-2)       asm volatile("s_waitcnt vmcnt(2)" ::: "memory");
    else if (s == NT-2) asm volatile("s_waitcnt vmcnt(0)" ::: "memory");
    __builtin_amdgcn_s_barrier();
  }

  #pragma unroll
  for (int j = 0; j < 2; ++j){
    const int n = bn*128 + wn*32 + j*16 + l15;
    const float bb = bias[n];
    #pragma unroll
    for (int i = 0; i < 8; ++i){
      const size_t m0 = (size_t)bm*256 + wm*128 + i*16 + l4*4;
      #pragma unroll
      for (int r = 0; r < 4; ++r)
        C[(m0 + r)*1024 + n] = f2bf(acc[i][j][r] + bb);
    }
  }
#undef STG_A
#undef STG_B
}

// ---------------- flash attention: 3-buffer K/V ring, counted vmcnt ----------
__global__ __launch_bounds__(512, 4) void attn_k(
    const uint16_t* __restrict__ Yqk, const uint16_t* __restrict__ Vt,
    uint16_t* __restrict__ att){
  extern __shared__ uint8_t lds[];
  const int tid = threadIdx.x;
  const int lane = tid & 63, wid = tid >> 6;
  const int l15 = lane & 15, l4 = lane >> 4;
  const int i = blockIdx.x;
  const int inst = (i & 7)*16 + ((i >> 3) & 15);
  const int qb = i >> 7;
  const int h = inst & 15, cb = inst >> 4;
  const size_t yrow0 = (size_t)cb * SA;
  const int q0 = qb*256 + wid*32;
  const size_t vbase = (size_t)inst * 64 * SPAD;
  const uint16_t* Yk = Yqk + yrow0*2048 + 1024 + h*64;

  short8 qf[2][2];
  #pragma unroll
  for (int u = 0; u < 2; ++u){
    const uint16_t* p = Yqk + (yrow0 + q0 + u*16 + l15)*2048 + h*64 + l4*8;
    qf[u][0] = *(const short8*)p;
    qf[u][1] = *(const short8*)(p + 32);
  }

  f32x4 o0[4], o1[4];
  float psum0 = 0.f, psum1 = 0.f;
  #pragma unroll
  for (int d = 0; d < 4; ++d){ o0[d] = (f32x4){0,0,0,0}; o1[d] = (f32x4){0,0,0,0}; }

  int koff[2], koffp[2], pwo[4];
  #pragma unroll
  for (int kk = 0; kk < 2; ++kk){
    koff[kk]  = (l15*128 + kk*64 + l4*16) ^ ((l15 & 7) << 4);
    koffp[kk] = l15*144 + kk*64 + l4*16;
  }
  #pragma unroll
  for (int nt = 0; nt < 4; ++nt)
    pwo[nt] = l15*144 + nt*32 + l4*8;
  uint8_t* const pb = lds + 49152 + wid*2304;

  const int srow = lane >> 3, schunk = lane & 7;
  const int strow = wid*8 + srow;
  const int sgch = schunk ^ srow;

#define ASTAGE(t3, kt) do { \
    gload16(Yk + (size_t)((kt)*64 + strow)*2048 + sgch*8, lds + (t3)*8192 + wid*1024); \
    gload16(Vt + vbase + (size_t)strow*SPAD + (kt)*64 + sgch*8, lds + 24576 + (t3)*8192 + wid*1024); \
  } while(0)

  ASTAGE(0, 0);
  ASTAGE(1, 1);
  asm volatile("s_waitcnt vmcnt(2)" ::: "memory");
  __builtin_amdgcn_s_barrier();

  for (int kt = 0; kt < 17; ++kt){
    const int c3 = kt % 3;
    if (kt <= 14){ const int t3 = (kt + 2) % 3; ASTAGE(t3, kt + 2); }
    const uint8_t* bK = lds + c3*8192;
    const uint8_t* bV = lds + 24576 + c3*8192;

    f32x4 sa[4], sb[4];
    #pragma unroll
    for (int nt = 0; nt < 4; ++nt){
      const short8 k0 = *(const short8*)(bK + nt*2048 + koff[0]);
      const short8 k1 = *(const short8*)(bK + nt*2048 + koff[1]);
      sa[nt] = mfma16(k1, qf[0][1], mfma16(k0, qf[0][0], (f32x4){0,0,0,0}));
      sb[nt] = mfma16(k1, qf[1][1], mfma16(k0, qf[1][0], (f32x4){0,0,0,0}));
    }
    if (kt == 16){
      #pragma unroll
      for (int nt = 0; nt < 4; ++nt)
        #pragma unroll
        for (int r = 0; r < 4; ++r){
          if (nt*16 + l4*4 + r >= 3){ sa[nt][r] = -3e38f; sb[nt][r] = -3e38f; }
        }
    }
    #pragma unroll
    for (int nt = 0; nt < 4; ++nt){
      const float p0 = __builtin_amdgcn_exp2f(sa[nt][0]);
      const float p1 = __builtin_amdgcn_exp2f(sa[nt][1]);
      const float p2 = __builtin_amdgcn_exp2f(sa[nt][2]);
      const float p3 = __builtin_amdgcn_exp2f(sa[nt][3]);
      psum0 += (p0 + p1) + (p2 + p3);
      uint32_t w0, w1;
      asm("v_cvt_pk_bf16_f32 %0, %1, %2" : "=v"(w0) : "v"(p0), "v"(p1));
      asm("v_cvt_pk_bf16_f32 %0, %1, %2" : "=v"(w1) : "v"(p2), "v"(p3));
      *(u32x2*)(pb + pwo[nt]) = (u32x2){w0, w1};
    }
    short8 vf[4][2];
    #pragma unroll
    for (int dt = 0; dt < 4; ++dt){
      vf[dt][0] = *(const short8*)(bV + dt*2048 + koff[0]);
      vf[dt][1] = *(const short8*)(bV + dt*2048 + koff[1]);
    }
    #pragma unroll
    for (int kk = 0; kk < 2; ++kk){
      const short8 pf = *(const short8*)(pb + koffp[kk]);
      #pragma unroll
      for (int dt = 0; dt < 4; ++dt)
        o0[dt] = mfma16(pf, vf[dt][kk], o0[dt]);
    }
    #pragma unroll
    for (int nt = 0; nt < 4; ++nt){
      const float p0 = __builtin_amdgcn_exp2f(sb[nt][0]);
      const float p1 = __builtin_amdgcn_exp2f(sb[nt][1]);
      const float p2 = __builtin_amdgcn_exp2f(sb[nt][2]);
      const float p3 = __builtin_amdgcn_exp2f(sb[nt][3]);
      psum1 += (p0 + p1) + (p2 + p3);
      uint32_t w0, w1;
      asm("v_cvt_pk_bf16_f32 %0, %1, %2" : "=v"(w0) : "v"(p0), "v"(p1));
      asm("v_cvt_pk_bf16_f32 %0, %1, %2" : "=v"(w1) : "v"(p2), "v"(p3));
      *(u32x2*)(pb + pwo[nt]) = (u32x2){w0, w1};
    }
    #pragma unroll
    for (int kk = 0; kk < 2; ++kk){
      const short8 pf = *(const short8*)(pb + koffp[kk]);
      #pragma unroll
      for (int dt = 0; dt < 4; ++dt)
        o1[dt] = mfma16(pf, vf[dt][kk], o1[dt]);
    }
    if (kt <= 14)      asm volatile("s_waitcnt vmcnt(2)" ::: "memory");
    else if (kt == 15) asm volatile("s_waitcnt vmcnt(0)" ::: "memory");
    if (kt <= 15) __builtin_amdgcn_s_barrier();
  }
#undef ASTAGE

  psum0 += __shfl_xor(psum0, 16); psum0 += __shfl_xor(psum0, 32);
  psum1 += __shfl_xor(psum1, 16); psum1 += __shfl_xor(psum1, 32);
  const size_t arow0 = (size_t)cb*1024 + q0;
  #pragma unroll
  for (int r = 0; r < 4; ++r){
    const float inv0 = 1.f / __shfl(psum0, l4*4 + r);
    const float inv1 = 1.f / __shfl(psum1, l4*4 + r);
    #pragma unroll
    for (int dt = 0; dt < 4; ++dt){
      att[(arow0 + l4*4 + r)*1024 + h*64 + dt*16 + l15] = f2bf(o0[dt][r] * inv0);
      att[(arow0 + 16 + l4*4 + r)*1024 + h*64 + dt*16 + l15] = f2bf(o1[dt][r] * inv1);
    }
  }
}

// ---------------- fused residual + LayerNorm -> f32 out ----------------
__global__ __launch_bounds__(256) void ln_out(
    const uint16_t* __restrict__ Op, const float* __restrict__ cnn,
    const float* __restrict__ llm, const float* __restrict__ g,
    const float* __restrict__ b, float* __restrict__ out){
  const int row = blockIdx.x;
  const int c = row >> 12, bq = row & 4095;
  const int tid = threadIdx.x;
  const ushort4 u = *(const ushort4*)(Op + (size_t)row*1024 + (tid<<2));
  const float4 rv = *(const float4*)((c ? llm : cnn) + (size_t)bq*1024 + (tid<<2));
  const float x0 = bf2f(u.x) + rv.x;
  const float x1 = bf2f(u.y) + rv.y;
  const float x2 = bf2f(u.z) + rv.z;
  const float x3 = bf2f(u.w) + rv.w;
  float s1 = x0+x1+x2+x3;
  float s2 = x0*x0+x1*x1+x2*x2+x3*x3;
  #pragma unroll
  for (int m=1;m<64;m<<=1){ s1 += __shfl_xor(s1,m); s2 += __shfl_xor(s2,m); }
  __shared__ float r1[4], r2[4];
  const int wid = tid >> 6, lane = tid & 63;
  if (lane == 0){ r1[wid] = s1; r2[wid] = s2; }
  __syncthreads();
  s1 = r1[0]+r1[1]+r1[2]+r1[3];
  s2 = r2[0]+r2[1]+r2[2]+r2[3];
  const float mu = s1 * 0.0009765625f;
  const float var = s2 * 0.0009765625f - mu*mu;
  const float rs = rsqrtf(var + 1e-5f);
  const float4 gv = *(const float4*)(g + (tid<<2));
  const float4 bv = *(const float4*)(b + (tid<<2));
  float4 ov;
  ov.x = (x0 - mu)*rs*gv.x + bv.x;
  ov.y = (x1 - mu)*rs*gv.y + bv.y;
  ov.z = (x2 - mu)*rs*gv.z + bv.z;
  ov.w = (x3 - mu)*rs*gv.w + bv.w;
  *(float4*)(out + ((size_t)c << 22) + (size_t)bq*1024 + (tid<<2)) = ov;
}

extern "C" void kernel_launch(void* const* d_in, const int* in_sizes, int n_in,
                              void* d_out, int out_size, void* d_ws, size_t ws_size,
                              hipStream_t stream){
  const float* cnn = (const float*)d_in[0];
  const float* llm = (const float*)d_in[1];
  const float* Wq  = (const float*)d_in[2];
  const float* bq  = (const float*)d_in[3];
  const float* Wk  = (const float*)d_in[4];
  const float* bk  = (const float*)d_in[5];
  const float* Wv  = (const float*)d_in[6];
  const float* bv  = (const float*)d_in[7];
  const float* Wo  = (const float*)d_in[8];
  const float* bo  = (const float*)d_in[9];
  const float* lng = (const float*)d_in[10];
  const float* lnb = (const float*)d_in[11];
  const float* ee  = (const float*)d_in[12];
  const float* em  = (const float*)d_in[13];
  const float* ep  = (const float*)d_in[14];

  uint8_t* ws = (uint8_t*)d_ws;
  uint16_t* X    = (uint16_t*)(ws + 0);           // 8192*1024*2 = 16,777,216
  uint16_t* W    = (uint16_t*)(ws + 16777216);    //  8,388,608
  float*    bias = (float*)   (ws + 25165824);    //     16,384
  uint16_t* Yqk  = (uint16_t*)(ws + 25182208);    // 8448*2048*2 = 34,603,008
  uint16_t* Vt   = (uint16_t*)(ws + 59785216);    // 8192*1088*2 = 17,825,792
  uint16_t* att  = X;                              // X dead after QKV GEMM
  uint16_t* Op   = Yqk;                            // Yqk dead after attn
  float* out = (float*)d_out;

  hipFuncSetAttribute((const void*)qkv128,
                      hipFuncAttributeMaxDynamicSharedMemorySize, 81920);
  hipFuncSetAttribute((const void*)oproj256,
                      hipFuncAttributeMaxDynamicSharedMemorySize, 98304);
  hipFuncSetAttribute((const void*)attn_k,
                      hipFuncAttributeMaxDynamicSharedMemorySize, 67584);

  prep_wb<<<4100, 256, 0, stream>>>(Wq, Wk, Wv, Wo, bq, bk, bv, bo, W, bias);
  prep_X<<<4096, 256, 0, stream>>>(cnn, llm, X);
  phys_qkv<<<24, 256, 0, stream>>>(ee, em, ep, W, bias, Yqk, Vt);
  qkv128<<<1024, 512, 81920, stream>>>(X, W, bias, Yqk, Vt);
  attn_k<<<512, 512, 67584, stream>>>(Yqk, Vt, att);
  oproj256<<<256, 512, 98304, stream>>>(att, W + 3145728, bias + 3072, Op);
  ln_out<<<8192, 256, 0, stream>>>(Op, cnn, llm, lng, lnb, out);
}

// Round 13
// 170.465 us; speedup vs baseline: 1.0733x; 1.0109x over previous
//
#include <hip/hip_runtime.h>
#include <stdint.h>

#define SA 1027
#define SPAD 1088

typedef __attribute__((ext_vector_type(8))) short short8;
typedef __attribute__((ext_vector_type(4))) float f32x4;
typedef __attribute__((ext_vector_type(2))) unsigned int u32x2;

typedef const __attribute__((address_space(1))) uint8_t* gas1;
typedef __attribute__((address_space(3))) uint8_t* las3;

__device__ __forceinline__ void gload16(const void* g, void* l){
  __builtin_amdgcn_global_load_lds((gas1)g, (las3)l, 16, 0, 0);
}

__device__ __forceinline__ uint16_t f2bf(float f){
  uint32_t x = __builtin_bit_cast(uint32_t, f);
  x = (x + 0x7fffu + ((x >> 16) & 1u)) >> 16;
  return (uint16_t)x;
}
__device__ __forceinline__ float bf2f(uint16_t u){
  uint32_t x = ((uint32_t)u) << 16;
  return __builtin_bit_cast(float, x);
}

__device__ __forceinline__ f32x4 mfma16(short8 a, short8 b, f32x4 c){
  return __builtin_amdgcn_mfma_f32_16x16x32_bf16(a, b, c, 0, 0, 0);
}

// log2(e)/8 — folded into Q at the QKV GEMM epilogue
#define QSCALE 0.18033688011112042f

// ---------------- prep: weights/biases -> bf16 ws ----------------
__global__ __launch_bounds__(256) void prep_wb(
    const float* __restrict__ Wq, const float* __restrict__ Wk,
    const float* __restrict__ Wv, const float* __restrict__ Wo,
    const float* __restrict__ bq, const float* __restrict__ bk,
    const float* __restrict__ bv, const float* __restrict__ bo,
    uint16_t* __restrict__ W, float* __restrict__ bias){
  const int gid = blockIdx.x*256 + threadIdx.x;
  if (gid < 1048576){
    const int w = gid >> 18;
    const int off = (gid & 262143) << 2;
    const float* src = (w==0) ? Wq : (w==1) ? Wk : (w==2) ? Wv : Wo;
    const float4 v = *(const float4*)(src + off);
    ushort4 u;
    u.x = f2bf(v.x); u.y = f2bf(v.y); u.z = f2bf(v.z); u.w = f2bf(v.w);
    *(ushort4*)(W + ((size_t)w << 20) + off) = u;
  } else if (gid < 1048576 + 1024){
    const int i = (gid - 1048576) << 2;
    const int w = i >> 10;
    const int off = i & 1023;
    const float* src = (w==0) ? bq : (w==1) ? bk : (w==2) ? bv : bo;
    *(float4*)(bias + i) = *(const float4*)(src + off);
  }
}

// ---------------- prep: X = seq rows (8192) bf16; 2 rows/block ----------------
__global__ __launch_bounds__(256) void prep_X(
    const float* __restrict__ cnn, const float* __restrict__ llm,
    uint16_t* __restrict__ X){
  const int row = blockIdx.x*2 + (threadIdx.x >> 7);
  const int c8 = (threadIdx.x & 127) << 3;
  const int cb = row >> 10, s = row & 1023;
  const int c = cb >> 2, b = cb & 3;
  const float* src = (c ? llm : cnn) + ((size_t)(b*1024 + s))*1024 + c8;
  const float4 v0 = *(const float4*)src;
  const float4 v1 = *(const float4*)(src + 4);
  short8 u;
  u[0]=(short)f2bf(v0.x); u[1]=(short)f2bf(v0.y); u[2]=(short)f2bf(v0.z); u[3]=(short)f2bf(v0.w);
  u[4]=(short)f2bf(v1.x); u[5]=(short)f2bf(v1.y); u[6]=(short)f2bf(v1.z); u[7]=(short)f2bf(v1.w);
  *(short8*)(X + (size_t)row*1024 + c8) = u;
}

// ---------------- phys rows: K,V projections of the 3 shared physics rows ----
__global__ __launch_bounds__(256) void phys_qkv(
    const float* __restrict__ ee, const float* __restrict__ em,
    const float* __restrict__ ep, const uint16_t* __restrict__ W,
    const float* __restrict__ bias, uint16_t* __restrict__ Yqk,
    uint16_t* __restrict__ Vt){
  __shared__ float xs[1024];
  const int t = blockIdx.x >> 3;
  const int col = 1024 + (blockIdx.x & 7)*256 + threadIdx.x;   // 1024..3071
  const float* e = (t==0) ? ee : (t==1) ? em : ep;
  for (int k = threadIdx.x; k < 1024; k += 256) xs[k] = bf2f(f2bf(e[k]));
  __syncthreads();
  const uint16_t* wr = W + (size_t)col*1024;
  float acc = 0.f;
  for (int k = 0; k < 1024; k += 8){
    const short8 w8 = *(const short8*)(wr + k);
    #pragma unroll
    for (int u = 0; u < 8; ++u) acc += bf2f((uint16_t)w8[u]) * xs[k+u];
  }
  const uint16_t o = f2bf(acc + bias[col]);
  if (col < 2048){
    #pragma unroll
    for (int cb = 0; cb < 8; ++cb)
      Yqk[((size_t)cb*SA + 1024 + t)*2048 + col] = o;
  } else {
    const int hd = col - 2048;
    #pragma unroll
    for (int cb = 0; cb < 8; ++cb)
      Vt[((size_t)(cb*1024 + hd))*SPAD + 1024 + t] = o;
  }
}

// ---------------- QKV: 128x192 2-phase GEMM, 80KB LDS -> 2 blocks/CU --------
// M=8192 N=3072 K=1024. grid 1024 = 64bm x 16bn = 4 exact rounds at 2/CU.
// 8 waves (2M x 4N), wave tile 64x48, acc[4][3]. Proven 58.4-58.8us.
__global__ __launch_bounds__(512, 4) void qkv128(
    const uint16_t* __restrict__ A, const uint16_t* __restrict__ B,
    const float* __restrict__ bias, uint16_t* __restrict__ Yqk,
    uint16_t* __restrict__ Vt){
  extern __shared__ uint8_t lds[];   // buf b at b*40960: A 16KB, B at +16384 (24KB)
  const int tid = threadIdx.x;
  const int lane = tid & 63, wid = tid >> 6;
  const int l15 = lane & 15, l4 = lane >> 4;
  const int wm = wid >> 2, wn = wid & 3;
  const int wg = (blockIdx.x & 7)*128 + (blockIdx.x >> 3);
  const int bm = wg >> 4, bn = wg & 15;

  const uint16_t* Ag = A + (size_t)bm*128*1024;
  const uint16_t* Bg = B + (size_t)bn*192*1024;

  const int srow8 = lane >> 3;
  const int gch = (lane & 7) ^ srow8;
  const int c0 = wid*2, c1 = c0 + 1;
  const size_t ga0 = (size_t)(c0*8 + srow8)*1024 + gch*8;
  const size_t ga1 = (size_t)(c1*8 + srow8)*1024 + gch*8;
  const size_t gb0 = (size_t)((wid*3+0)*8 + srow8)*1024 + gch*8;
  const size_t gb1 = (size_t)((wid*3+1)*8 + srow8)*1024 + gch*8;
  const size_t gb2 = (size_t)((wid*3+2)*8 + srow8)*1024 + gch*8;

#define STG_A(buf, kt) do { \
    gload16(Ag + (size_t)(kt)*64 + ga0, lds + (buf)*40960 + c0*1024); \
    gload16(Ag + (size_t)(kt)*64 + ga1, lds + (buf)*40960 + c1*1024); \
  } while(0)
#define STG_B(buf, kt) do { \
    gload16(Bg + (size_t)(kt)*64 + gb0, lds + (buf)*40960 + 16384 + (wid*3+0)*1024); \
    gload16(Bg + (size_t)(kt)*64 + gb1, lds + (buf)*40960 + 16384 + (wid*3+1)*1024); \
    gload16(Bg + (size_t)(kt)*64 + gb2, lds + (buf)*40960 + 16384 + (wid*3+2)*1024); \
  } while(0)

  int koff[2];
  koff[0] = (l4*16) ^ ((l15 & 7) << 4);
  koff[1] = (64 + l4*16) ^ ((l15 & 7) << 4);
  const int arow = (wm*64 + l15) * 128;
  const int bbase = 16384 + (wn*48 + l15) * 128;

  f32x4 acc[4][3];
  #pragma unroll
  for (int i = 0; i < 4; ++i)
    #pragma unroll
    for (int j = 0; j < 3; ++j) acc[i][j] = (f32x4){0.f,0.f,0.f,0.f};

  const int NT = 16;
  STG_A(0,0); STG_B(0,0); STG_B(1,1);
  asm volatile("s_waitcnt vmcnt(3)" ::: "memory");
  __builtin_amdgcn_s_barrier();

  for (int s = 0; s < NT; ++s){
    const int b = s & 1, nb = b ^ 1;
    const uint8_t* L = lds + b*40960;
    short8 af[2][2], af2[2][2], bfr[3][2];

    // ---- phase 0: rows wm*64+0..31 x all 3 B frags
    if (s+1 < NT){ STG_A(nb, s+1); }
    #pragma unroll
    for (int i = 0; i < 2; ++i){
      af[i][0] = *(const short8*)(L + arow + i*2048 + koff[0]);
      af[i][1] = *(const short8*)(L + arow + i*2048 + koff[1]);
    }
    #pragma unroll
    for (int j = 0; j < 3; ++j){
      bfr[j][0] = *(const short8*)(L + bbase + j*2048 + koff[0]);
      bfr[j][1] = *(const short8*)(L + bbase + j*2048 + koff[1]);
    }
    __builtin_amdgcn_s_barrier();
    asm volatile("s_waitcnt lgkmcnt(0)" ::: "memory");
    __builtin_amdgcn_s_setprio(1);
    #pragma unroll
    for (int i = 0; i < 2; ++i)
      #pragma unroll
      for (int j = 0; j < 3; ++j)
        acc[i][j] = mfma16(af[i][1], bfr[j][1], mfma16(af[i][0], bfr[j][0], acc[i][j]));
    __builtin_amdgcn_s_setprio(0);
    __builtin_amdgcn_s_barrier();

    // ---- phase 1: rows wm*64+32..63 (B frags reused from regs)
    if (s+2 < NT){ STG_B(b, s+2); }   // B(b) dead after phase-0 barrier
    #pragma unroll
    for (int i = 0; i < 2; ++i){
      af2[i][0] = *(const short8*)(L + arow + 4096 + i*2048 + koff[0]);
      af2[i][1] = *(const short8*)(L + arow + 4096 + i*2048 + koff[1]);
    }
    __builtin_amdgcn_s_barrier();
    asm volatile("s_waitcnt lgkmcnt(0)" ::: "memory");
    __builtin_amdgcn_s_setprio(1);
    #pragma unroll
    for (int i = 0; i < 2; ++i)
      #pragma unroll
      for (int j = 0; j < 3; ++j)
        acc[i+2][j] = mfma16(af2[i][1], bfr[j][1], mfma16(af2[i][0], bfr[j][0], acc[i+2][j]));
    __builtin_amdgcn_s_setprio(0);
    if (s < NT-2)       asm volatile("s_waitcnt vmcnt(3)" ::: "memory");
    else if (s == NT-2) asm volatile("s_waitcnt vmcnt(0)" ::: "memory");
    __builtin_amdgcn_s_barrier();
  }

  // epilogue: Q/K -> Yqk (row remap), V -> Vt transposed
  #pragma unroll
  for (int j = 0; j < 3; ++j){
    const int n = bn*192 + wn*48 + j*16 + l15;
    const float bb = bias[n];
    if (n < 2048){
      const float sc = (n < 1024) ? QSCALE : 1.0f;
      #pragma unroll
      for (int i = 0; i < 4; ++i){
        const int m0 = bm*128 + wm*64 + i*16 + l4*4;
        #pragma unroll
        for (int r = 0; r < 4; ++r){
          const int m = m0 + r;
          Yqk[((size_t)(m >> 10)*SA + (m & 1023))*2048 + n] = f2bf((acc[i][j][r] + bb) * sc);
        }
      }
    } else {
      const int hd = n - 2048;
      #pragma unroll
      for (int i = 0; i < 4; ++i){
        const int m0 = bm*128 + wm*64 + i*16 + l4*4;
        const size_t vrow = (size_t)(m0 >> 10)*1024 + hd;
        const uint32_t w0 = (uint32_t)f2bf(acc[i][j][0] + bb) | ((uint32_t)f2bf(acc[i][j][1] + bb) << 16);
        const uint32_t w1 = (uint32_t)f2bf(acc[i][j][2] + bb) | ((uint32_t)f2bf(acc[i][j][3] + bb) << 16);
        *(u32x2*)(Vt + vrow*SPAD + (m0 & 1023)) = (u32x2){w0, w1};
      }
    }
  }
#undef STG_A
#undef STG_B
}

// ---------------- oproj: 128x128 2-phase GEMM, 64KB LDS -> 2 blocks/CU ------
// M=8192 N=1024. grid 512 = 64bm x 8bn = 2 exact rounds at 2/CU. (R10 version)
__global__ __launch_bounds__(512, 4) void oproj128(
    const uint16_t* __restrict__ A, const uint16_t* __restrict__ B,
    const float* __restrict__ bias, uint16_t* __restrict__ C){
  extern __shared__ uint8_t lds[];   // buf b at b*32768: A 16KB, B at +16384
  const int tid = threadIdx.x;
  const int lane = tid & 63, wid = tid >> 6;
  const int l15 = lane & 15, l4 = lane >> 4;
  const int wm = wid >> 2, wn = wid & 3;
  const int wg = (blockIdx.x & 7)*64 + (blockIdx.x >> 3);   // 512 blocks
  const int bm = wg >> 3, bn = wg & 7;

  const uint16_t* Ag = A + (size_t)bm*128*1024;
  const uint16_t* Bg = B + (size_t)bn*128*1024;

  const int srow8 = lane >> 3;
  const int gch = (lane & 7) ^ srow8;
  const int c0 = wid*2, c1 = c0 + 1;
  const size_t ga0 = (size_t)(c0*8 + srow8)*1024 + gch*8;
  const size_t ga1 = (size_t)(c1*8 + srow8)*1024 + gch*8;

#define STG_A(buf, kt) do { \
    gload16(Ag + (size_t)(kt)*64 + ga0, lds + (buf)*32768 + c0*1024); \
    gload16(Ag + (size_t)(kt)*64 + ga1, lds + (buf)*32768 + c1*1024); \
  } while(0)
#define STG_B(buf, kt) do { \
    gload16(Bg + (size_t)(kt)*64 + ga0, lds + (buf)*32768 + 16384 + c0*1024); \
    gload16(Bg + (size_t)(kt)*64 + ga1, lds + (buf)*32768 + 16384 + c1*1024); \
  } while(0)

  int koff[2];
  koff[0] = (l4*16) ^ ((l15 & 7) << 4);
  koff[1] = (64 + l4*16) ^ ((l15 & 7) << 4);
  const int arow = (wm*64 + l15) * 128;
  const int bbase = 16384 + (wn*32 + l15) * 128;

  f32x4 acc[4][2];
  #pragma unroll
  for (int i = 0; i < 4; ++i){ acc[i][0] = (f32x4){0,0,0,0}; acc[i][1] = (f32x4){0,0,0,0}; }

  const int NT = 16;
  STG_A(0,0); STG_B(0,0); STG_B(1,1);
  asm volatile("s_waitcnt vmcnt(2)" ::: "memory");
  __builtin_amdgcn_s_barrier();

  for (int s = 0; s < NT; ++s){
    const int b = s & 1, nb = b ^ 1;
    const uint8_t* L = lds + b*32768;
    short8 af[2][2], af2[2][2], bfr[2][2];

    // ---- phase 0
    if (s+1 < NT){ STG_A(nb, s+1); }
    #pragma unroll
    for (int i = 0; i < 2; ++i){
      af[i][0] = *(const short8*)(L + arow + i*2048 + koff[0]);
      af[i][1] = *(const short8*)(L + arow + i*2048 + koff[1]);
    }
    #pragma unroll
    for (int j = 0; j < 2; ++j){
      bfr[j][0] = *(const short8*)(L + bbase + j*2048 + koff[0]);
      bfr[j][1] = *(const short8*)(L + bbase + j*2048 + koff[1]);
    }
    __builtin_amdgcn_s_barrier();
    asm volatile("s_waitcnt lgkmcnt(0)" ::: "memory");
    __builtin_amdgcn_s_setprio(1);
    #pragma unroll
    for (int i = 0; i < 2; ++i)
      #pragma unroll
      for (int j = 0; j < 2; ++j)
        acc[i][j] = mfma16(af[i][1], bfr[j][1], mfma16(af[i][0], bfr[j][0], acc[i][j]));
    __builtin_amdgcn_s_setprio(0);
    __builtin_amdgcn_s_barrier();

    // ---- phase 1
    if (s+2 < NT){ STG_B(b, s+2); }
    #pragma unroll
    for (int i = 0; i < 2; ++i){
      af2[i][0] = *(const short8*)(L + arow + 4096 + i*2048 + koff[0]);
      af2[i][1] = *(const short8*)(L + arow + 4096 + i*2048 + koff[1]);
    }
    __builtin_amdgcn_s_barrier();
    asm volatile("s_waitcnt lgkmcnt(0)" ::: "memory");
    __builtin_amdgcn_s_setprio(1);
    #pragma unroll
    for (int i = 0; i < 2; ++i)
      #pragma unroll
      for (int j = 0; j < 2; ++j)
        acc[i+2][j] = mfma16(af2[i][1], bfr[j][1], mfma16(af2[i][0], bfr[j][0], acc[i+2][j]));
    __builtin_amdgcn_s_setprio(0);
    if (s < NT-2)       asm volatile("s_waitcnt vmcnt(2)" ::: "memory");
    else if (s == NT-2) asm volatile("s_waitcnt vmcnt(0)" ::: "memory");
    __builtin_amdgcn_s_barrier();
  }

  #pragma unroll
  for (int j = 0; j < 2; ++j){
    const int n = bn*128 + wn*32 + j*16 + l15;
    const float bb = bias[n];
    #pragma unroll
    for (int i = 0; i < 4; ++i){
      const size_t m0 = (size_t)bm*128 + wm*64 + i*16 + l4*4;
      #pragma unroll
      for (int r = 0; r < 4; ++r)
        C[(m0 + r)*1024 + n] = f2bf(acc[i][j][r] + bb);
    }
  }
#undef STG_A
#undef STG_B
}

// ---------------- flash attention: 3-buffer K/V ring, counted vmcnt ----------
__global__ __launch_bounds__(512, 4) void attn_k(
    const uint16_t* __restrict__ Yqk, const uint16_t* __restrict__ Vt,
    uint16_t* __restrict__ att){
  extern __shared__ uint8_t lds[];
  const int tid = threadIdx.x;
  const int lane = tid & 63, wid = tid >> 6;
  const int l15 = lane & 15, l4 = lane >> 4;
  const int i = blockIdx.x;
  const int inst = (i & 7)*16 + ((i >> 3) & 15);
  const int qb = i >> 7;
  const int h = inst & 15, cb = inst >> 4;
  const size_t yrow0 = (size_t)cb * SA;
  const int q0 = qb*256 + wid*32;
  const size_t vbase = (size_t)inst * 64 * SPAD;
  const uint16_t* Yk = Yqk + yrow0*2048 + 1024 + h*64;

  short8 qf[2][2];
  #pragma unroll
  for (int u = 0; u < 2; ++u){
    const uint16_t* p = Yqk + (yrow0 + q0 + u*16 + l15)*2048 + h*64 + l4*8;
    qf[u][0] = *(const short8*)p;
    qf[u][1] = *(const short8*)(p + 32);
  }

  f32x4 o0[4], o1[4];
  float psum0 = 0.f, psum1 = 0.f;
  #pragma unroll
  for (int d = 0; d < 4; ++d){ o0[d] = (f32x4){0,0,0,0}; o1[d] = (f32x4){0,0,0,0}; }

  int koff[2], koffp[2], pwo[4];
  #pragma unroll
  for (int kk = 0; kk < 2; ++kk){
    koff[kk]  = (l15*128 + kk*64 + l4*16) ^ ((l15 & 7) << 4);
    koffp[kk] = l15*144 + kk*64 + l4*16;
  }
  #pragma unroll
  for (int nt = 0; nt < 4; ++nt)
    pwo[nt] = l15*144 + nt*32 + l4*8;
  uint8_t* const pb = lds + 49152 + wid*2304;

  const int srow = lane >> 3, schunk = lane & 7;
  const int strow = wid*8 + srow;
  const int sgch = schunk ^ srow;

#define ASTAGE(t3, kt) do { \
    gload16(Yk + (size_t)((kt)*64 + strow)*2048 + sgch*8, lds + (t3)*8192 + wid*1024); \
    gload16(Vt + vbase + (size_t)strow*SPAD + (kt)*64 + sgch*8, lds + 24576 + (t3)*8192 + wid*1024); \
  } while(0)

  ASTAGE(0, 0);
  ASTAGE(1, 1);
  asm volatile("s_waitcnt vmcnt(2)" ::: "memory");
  __builtin_amdgcn_s_barrier();

  for (int kt = 0; kt < 17; ++kt){
    const int c3 = kt % 3;
    if (kt <= 14){ const int t3 = (kt + 2) % 3; ASTAGE(t3, kt + 2); }
    const uint8_t* bK = lds + c3*8192;
    const uint8_t* bV = lds + 24576 + c3*8192;

    f32x4 sa[4], sb[4];
    #pragma unroll
    for (int nt = 0; nt < 4; ++nt){
      const short8 k0 = *(const short8*)(bK + nt*2048 + koff[0]);
      const short8 k1 = *(const short8*)(bK + nt*2048 + koff[1]);
      sa[nt] = mfma16(k1, qf[0][1], mfma16(k0, qf[0][0], (f32x4){0,0,0,0}));
      sb[nt] = mfma16(k1, qf[1][1], mfma16(k0, qf[1][0], (f32x4){0,0,0,0}));
    }
    if (kt == 16){
      #pragma unroll
      for (int nt = 0; nt < 4; ++nt)
        #pragma unroll
        for (int r = 0; r < 4; ++r){
          if (nt*16 + l4*4 + r >= 3){ sa[nt][r] = -3e38f; sb[nt][r] = -3e38f; }
        }
    }
    #pragma unroll
    for (int nt = 0; nt < 4; ++nt){
      const float p0 = __builtin_amdgcn_exp2f(sa[nt][0]);
      const float p1 = __builtin_amdgcn_exp2f(sa[nt][1]);
      const float p2 = __builtin_amdgcn_exp2f(sa[nt][2]);
      const float p3 = __builtin_amdgcn_exp2f(sa[nt][3]);
      psum0 += (p0 + p1) + (p2 + p3);
      uint32_t w0, w1;
      asm("v_cvt_pk_bf16_f32 %0, %1, %2" : "=v"(w0) : "v"(p0), "v"(p1));
      asm("v_cvt_pk_bf16_f32 %0, %1, %2" : "=v"(w1) : "v"(p2), "v"(p3));
      *(u32x2*)(pb + pwo[nt]) = (u32x2){w0, w1};
    }
    short8 vf[4][2];
    #pragma unroll
    for (int dt = 0; dt < 4; ++dt){
      vf[dt][0] = *(const short8*)(bV + dt*2048 + koff[0]);
      vf[dt][1] = *(const short8*)(bV + dt*2048 + koff[1]);
    }
    #pragma unroll
    for (int kk = 0; kk < 2; ++kk){
      const short8 pf = *(const short8*)(pb + koffp[kk]);
      #pragma unroll
      for (int dt = 0; dt < 4; ++dt)
        o0[dt] = mfma16(pf, vf[dt][kk], o0[dt]);
    }
    #pragma unroll
    for (int nt = 0; nt < 4; ++nt){
      const float p0 = __builtin_amdgcn_exp2f(sb[nt][0]);
      const float p1 = __builtin_amdgcn_exp2f(sb[nt][1]);
      const float p2 = __builtin_amdgcn_exp2f(sb[nt][2]);
      const float p3 = __builtin_amdgcn_exp2f(sb[nt][3]);
      psum1 += (p0 + p1) + (p2 + p3);
      uint32_t w0, w1;
      asm("v_cvt_pk_bf16_f32 %0, %1, %2" : "=v"(w0) : "v"(p0), "v"(p1));
      asm("v_cvt_pk_bf16_f32 %0, %1, %2" : "=v"(w1) : "v"(p2), "v"(p3));
      *(u32x2*)(pb + pwo[nt]) = (u32x2){w0, w1};
    }
    #pragma unroll
    for (int kk = 0; kk < 2; ++kk){
      const short8 pf = *(const short8*)(pb + koffp[kk]);
      #pragma unroll
      for (int dt = 0; dt < 4; ++dt)
        o1[dt] = mfma16(pf, vf[dt][kk], o1[dt]);
    }
    if (kt <= 14)      asm volatile("s_waitcnt vmcnt(2)" ::: "memory");
    else if (kt == 15) asm volatile("s_waitcnt vmcnt(0)" ::: "memory");
    if (kt <= 15) __builtin_amdgcn_s_barrier();
  }
#undef ASTAGE

  psum0 += __shfl_xor(psum0, 16); psum0 += __shfl_xor(psum0, 32);
  psum1 += __shfl_xor(psum1, 16); psum1 += __shfl_xor(psum1, 32);
  const size_t arow0 = (size_t)cb*1024 + q0;
  #pragma unroll
  for (int r = 0; r < 4; ++r){
    const float inv0 = 1.f / __shfl(psum0, l4*4 + r);
    const float inv1 = 1.f / __shfl(psum1, l4*4 + r);
    #pragma unroll
    for (int dt = 0; dt < 4; ++dt){
      att[(arow0 + l4*4 + r)*1024 + h*64 + dt*16 + l15] = f2bf(o0[dt][r] * inv0);
      att[(arow0 + 16 + l4*4 + r)*1024 + h*64 + dt*16 + l15] = f2bf(o1[dt][r] * inv1);
    }
  }
}

// ---------------- fused residual + LayerNorm -> f32 out ----------------
__global__ __launch_bounds__(256) void ln_out(
    const uint16_t* __restrict__ Op, const float* __restrict__ cnn,
    const float* __restrict__ llm, const float* __restrict__ g,
    const float* __restrict__ b, float* __restrict__ out){
  const int row = blockIdx.x;
  const int c = row >> 12, bq = row & 4095;
  const int tid = threadIdx.x;
  const ushort4 u = *(const ushort4*)(Op + (size_t)row*1024 + (tid<<2));
  const float4 rv = *(const float4*)((c ? llm : cnn) + (size_t)bq*1024 + (tid<<2));
  const float x0 = bf2f(u.x) + rv.x;
  const float x1 = bf2f(u.y) + rv.y;
  const float x2 = bf2f(u.z) + rv.z;
  const float x3 = bf2f(u.w) + rv.w;
  float s1 = x0+x1+x2+x3;
  float s2 = x0*x0+x1*x1+x2*x2+x3*x3;
  #pragma unroll
  for (int m=1;m<64;m<<=1){ s1 += __shfl_xor(s1,m); s2 += __shfl_xor(s2,m); }
  __shared__ float r1[4], r2[4];
  const int wid = tid >> 6, lane = tid & 63;
  if (lane == 0){ r1[wid] = s1; r2[wid] = s2; }
  __syncthreads();
  s1 = r1[0]+r1[1]+r1[2]+r1[3];
  s2 = r2[0]+r2[1]+r2[2]+r2[3];
  const float mu = s1 * 0.0009765625f;
  const float var = s2 * 0.0009765625f - mu*mu;
  const float rs = rsqrtf(var + 1e-5f);
  const float4 gv = *(const float4*)(g + (tid<<2));
  const float4 bv = *(const float4*)(b + (tid<<2));
  float4 ov;
  ov.x = (x0 - mu)*rs*gv.x + bv.x;
  ov.y = (x1 - mu)*rs*gv.y + bv.y;
  ov.z = (x2 - mu)*rs*gv.z + bv.z;
  ov.w = (x3 - mu)*rs*gv.w + bv.w;
  *(float4*)(out + ((size_t)c << 22) + (size_t)bq*1024 + (tid<<2)) = ov;
}

extern "C" void kernel_launch(void* const* d_in, const int* in_sizes, int n_in,
                              void* d_out, int out_size, void* d_ws, size_t ws_size,
                              hipStream_t stream){
  const float* cnn = (const float*)d_in[0];
  const float* llm = (const float*)d_in[1];
  const float* Wq  = (const float*)d_in[2];
  const float* bq  = (const float*)d_in[3];
  const float* Wk  = (const float*)d_in[4];
  const float* bk  = (const float*)d_in[5];
  const float* Wv  = (const float*)d_in[6];
  const float* bv  = (const float*)d_in[7];
  const float* Wo  = (const float*)d_in[8];
  const float* bo  = (const float*)d_in[9];
  const float* lng = (const float*)d_in[10];
  const float* lnb = (const float*)d_in[11];
  const float* ee  = (const float*)d_in[12];
  const float* em  = (const float*)d_in[13];
  const float* ep  = (const float*)d_in[14];

  uint8_t* ws = (uint8_t*)d_ws;
  uint16_t* X    = (uint16_t*)(ws + 0);           // 8192*1024*2 = 16,777,216
  uint16_t* W    = (uint16_t*)(ws + 16777216);    //  8,388,608
  float*    bias = (float*)   (ws + 25165824);    //     16,384
  uint16_t* Yqk  = (uint16_t*)(ws + 25182208);    // 8448*2048*2 = 34,603,008
  uint16_t* Vt   = (uint16_t*)(ws + 59785216);    // 8192*1088*2 = 17,825,792
  uint16_t* att  = X;                              // X dead after QKV GEMM
  uint16_t* Op   = Yqk;                            // Yqk dead after attn
  float* out = (float*)d_out;

  hipFuncSetAttribute((const void*)qkv128,
                      hipFuncAttributeMaxDynamicSharedMemorySize, 81920);
  hipFuncSetAttribute((const void*)oproj128,
                      hipFuncAttributeMaxDynamicSharedMemorySize, 65536);
  hipFuncSetAttribute((const void*)attn_k,
                      hipFuncAttributeMaxDynamicSharedMemorySize, 67584);

  prep_wb<<<4100, 256, 0, stream>>>(Wq, Wk, Wv, Wo, bq, bk, bv, bo, W, bias);
  prep_X<<<4096, 256, 0, stream>>>(cnn, llm, X);
  phys_qkv<<<24, 256, 0, stream>>>(ee, em, ep, W, bias, Yqk, Vt);
  qkv128<<<1024, 512, 81920, stream>>>(X, W, bias, Yqk, Vt);
  attn_k<<<512, 512, 67584, stream>>>(Yqk, Vt, att);
  oproj128<<<512, 512, 65536, stream>>>(att, W + 3145728, bias + 3072, Op);
  ln_out<<<8192, 256, 0, stream>>>(Op, cnn, llm, lng, lnb, out);
}